// Round 8
// baseline (199.124 us; speedup 1.0000x reference)
//
#include <hip/hip_runtime.h>
#include <math.h>

typedef short bf16x8 __attribute__((ext_vector_type(8)));
typedef float f32x4 __attribute__((ext_vector_type(4)));
typedef unsigned short u16x8 __attribute__((ext_vector_type(8)));

// Segments (cu_seqlens=[0,1024,2560,4096], searchsorted side='left'):
// seg0 [0,1025) len1025 ; seg1 [1025,2561) len1536 ; seg2 [2561,4096) len1535
// vT packed cols: pc(s) = s<1025 ? s : s+63 (seg0 @0 pad->1088, seg1 @1088, seg2 @2624); width 4160

__device__ __forceinline__ unsigned short f2b(float f) {
  union { float f; unsigned int u; } v; v.f = f;
  unsigned int u = v.u;
  return (unsigned short)((u + 0x7FFFu + ((u >> 16) & 1u)) >> 16);  // RTNE
}
__device__ __forceinline__ float b2f(unsigned short h) {
  union { unsigned int u; float f; } v; v.u = ((unsigned int)h) << 16; return v.f;
}

// ---- RoPE cos/sin table: [4096][32] each, f32 ----
__global__ __launch_bounds__(256) void k_tables(float* __restrict__ cosT, float* __restrict__ sinT) {
  int idx = blockIdx.x * 256 + threadIdx.x;
  if (idx >= 4096 * 32) return;
  int pos = idx >> 5, i = idx & 31;
  float invf = (float)(1.0 / pow(10000.0, (double)i / 32.0));
  float ang = (float)pos * invf;
  cosT[idx] = cosf(ang);
  sinT[idx] = sinf(ang);
}

// ---- zero vT pad columns (runs BEFORE k_gemm_qkv) ----
__global__ __launch_bounds__(256) void k_vpad(unsigned short* __restrict__ vT) {
  int h = blockIdx.x, t = threadIdx.x;
  for (int i = t; i < 64 * 64; i += 256) {
    int d = i >> 6, c = i & 63;
    vT[((size_t)(h * 64 + d)) * 4160 + 1024 + c] = 0;
  }
  if (t < 64) vT[((size_t)(h * 64 + t)) * 4160 + 4159] = 0;
}

__global__ __launch_bounds__(256) void k_cvt(const float* __restrict__ x, unsigned short* __restrict__ xb, int n4) {
  int idx = blockIdx.x * 256 + threadIdx.x;
  if (idx >= n4) return;
  float4 v = ((const float4*)x)[idx];
  ushort4 o; o.x = f2b(v.x); o.y = f2b(v.y); o.z = f2b(v.z); o.w = f2b(v.w);
  ((ushort4*)xb)[idx] = o;
}

__global__ __launch_bounds__(256) void k_twcvt(const float* __restrict__ src, unsigned short* __restrict__ dst,
                                               int K, int N) {
  __shared__ float tile[32][33];
  int k0 = blockIdx.x * 32, n0 = blockIdx.y * 32;
  int t = threadIdx.x;
  for (int i = 0; i < 4; i++) {
    int e = t + i * 256; int r = e >> 5, c = e & 31;
    tile[r][c] = src[(size_t)(k0 + r) * N + n0 + c];
  }
  __syncthreads();
  for (int i = 0; i < 4; i++) {
    int e = t + i * 256; int r = e >> 5, c = e & 31;
    dst[(size_t)(n0 + r) * K + k0 + c] = f2b(tile[c][r]);
  }
}

// ---- generic NT GEMM (used for proj): C = A * Bt^T + bias, f32 out ----
__global__ __launch_bounds__(256) void k_gemm(const unsigned short* __restrict__ A,
                                              const unsigned short* __restrict__ Bt,
                                              const float* __restrict__ bias,
                                              float* __restrict__ C,
                                              int M, int N, int K) {
  __shared__ unsigned short As[64][72];
  __shared__ unsigned short Bs[64][72];
  int row0 = blockIdx.x * 64, col0 = blockIdx.y * 64;
  int t = threadIdx.x, w = t >> 6, l = t & 63;
  int l15 = l & 15, l4 = l >> 4;
  f32x4 acc[4] = {};
  for (int k0 = 0; k0 < K; k0 += 64) {
    for (int i = 0; i < 2; i++) {
      int e = t + i * 256; int r = e >> 3, c8 = e & 7;
      *(uint4*)&As[r][c8 * 8] = *(const uint4*)(A + (size_t)(row0 + r) * K + k0 + c8 * 8);
      *(uint4*)&Bs[r][c8 * 8] = *(const uint4*)(Bt + (size_t)(col0 + r) * K + k0 + c8 * 8);
    }
    __syncthreads();
    for (int kh = 0; kh < 2; kh++) {
      bf16x8 a = *(const bf16x8*)&As[w * 16 + l15][kh * 32 + l4 * 8];
      for (int cf = 0; cf < 4; cf++) {
        bf16x8 b = *(const bf16x8*)&Bs[cf * 16 + l15][kh * 32 + l4 * 8];
        acc[cf] = __builtin_amdgcn_mfma_f32_16x16x32_bf16(a, b, acc[cf], 0, 0, 0);
      }
    }
    __syncthreads();
  }
  for (int cf = 0; cf < 4; cf++) {
    int col = col0 + cf * 16 + l15;
    float bv = bias[col];
    for (int r = 0; r < 4; r++) {
      int row = row0 + w * 16 + l4 * 4 + r;
      C[(size_t)row * N + col] = acc[cf][r] + bv;
    }
  }
}

// ---- qkv GEMM with fused bias + RoPE + head-split + V-transpose epilogue ----
__global__ __launch_bounds__(256) void k_gemm_qkv(const unsigned short* __restrict__ A,
                                                  const unsigned short* __restrict__ Bt,
                                                  const float* __restrict__ bias,
                                                  const float* __restrict__ cosT,
                                                  const float* __restrict__ sinT,
                                                  unsigned short* __restrict__ qh,
                                                  unsigned short* __restrict__ kh,
                                                  unsigned short* __restrict__ vT) {
  __shared__ unsigned short As[64][72];
  __shared__ unsigned short Bs[64][72];
  int row0 = blockIdx.x * 64, col0 = blockIdx.y * 64;
  int t = threadIdx.x, w = t >> 6, l = t & 63;
  int l15 = l & 15, l4 = l >> 4;
  f32x4 acc[4] = {};
  for (int k0 = 0; k0 < 512; k0 += 64) {
    for (int i = 0; i < 2; i++) {
      int e = t + i * 256; int r = e >> 3, c8 = e & 7;
      *(uint4*)&As[r][c8 * 8] = *(const uint4*)(A + (size_t)(row0 + r) * 512 + k0 + c8 * 8);
      *(uint4*)&Bs[r][c8 * 8] = *(const uint4*)(Bt + (size_t)(col0 + r) * 512 + k0 + c8 * 8);
    }
    __syncthreads();
    for (int kk = 0; kk < 2; kk++) {
      bf16x8 a = *(const bf16x8*)&As[w * 16 + l15][kk * 32 + l4 * 8];
      for (int cf = 0; cf < 4; cf++) {
        bf16x8 b = *(const bf16x8*)&Bs[cf * 16 + l15][kk * 32 + l4 * 8];
        acc[cf] = __builtin_amdgcn_mfma_f32_16x16x32_bf16(a, b, acc[cf], 0, 0, 0);
      }
    }
    __syncthreads();
  }
  for (int cf = 0; cf < 4; cf++) {
    float bv = bias[col0 + cf * 16 + l15];
    for (int r = 0; r < 4; r++) acc[cf][r] += bv;
  }
  int kind = col0 >> 9;                 // 0=q, 1=k, 2=v
  int h = (col0 & 511) >> 6;
  if (kind < 2) {
    for (int r = 0; r < 4; r++) {
      int row = row0 + w * 16 + l4 * 4 + r;
      float c0 = cosT[row * 32 + l15],      s0 = sinT[row * 32 + l15];
      float c1 = cosT[row * 32 + 16 + l15], s1 = sinT[row * 32 + 16 + l15];
      float q0 = acc[0][r], q1 = acc[1][r], q2 = acc[2][r], q3 = acc[3][r];
      int rl = w * 16 + l4 * 4 + r;
      As[rl][0 * 16 + l15] = f2b(q0 * c0 - q2 * s0);
      As[rl][1 * 16 + l15] = f2b(q1 * c1 - q3 * s1);
      As[rl][2 * 16 + l15] = f2b(q2 * c0 + q0 * s0);
      As[rl][3 * 16 + l15] = f2b(q3 * c1 + q1 * s1);
    }
  } else {
    for (int cf = 0; cf < 4; cf++)
      for (int r = 0; r < 4; r++)
        As[w * 16 + l4 * 4 + r][cf * 16 + l15] = f2b(acc[cf][r]);
  }
  __syncthreads();
  if (kind < 2) {
    unsigned short* dst = (kind == 0 ? qh : kh);
    for (int p = 0; p < 2; p++) {
      int idx = p * 256 + t;
      int rl = idx >> 3, c8 = (idx & 7) * 8;
      *(u16x8*)(dst + ((size_t)(h * 4096 + row0 + rl)) * 64 + c8) = *(const u16x8*)&As[rl][c8];
    }
  } else {
    for (int p = 0; p < 2; p++) {
      int idx = p * 256 + t;
      int d = idx >> 3, s8 = (idx & 7) * 8;
      int sbase = row0 + s8;
      u16x8 val;
      for (int j = 0; j < 8; j++) val[j] = As[s8 + j][d];
      unsigned short* vrow = vT + ((size_t)(h * 64 + d)) * 4160;
      if (sbase != 1024) {
        int pc = (sbase < 1025) ? sbase : sbase + 63;
        *(u16x8*)(vrow + pc) = val;
      } else {
        for (int j = 0; j < 8; j++) {
          int s = sbase + j;
          vrow[(s < 1025) ? s : s + 63] = val[j];
        }
      }
    }
  }
}

// ---- denominator kernel: row sums of exp(QK^T/8) per 32-row strip -> Dn = 1/sum ----
template<int SEG>
__device__ __forceinline__ void dn_body(int h, int row0,
    const unsigned short* __restrict__ qh, const unsigned short* __restrict__ kh,
    float* __restrict__ Dn,
    unsigned short (&Ks)[64][72], float (&pd)[4][16]) {
  constexpr int LO  = SEG == 0 ? 0 : (SEG == 1 ? 1025 : 2561);
  constexpr int HI  = SEG == 0 ? 1025 : (SEG == 1 ? 2561 : 4096);
  constexpr int LEN = HI - LO;
  constexpr int NKT = SEG == 0 ? 17 : 24;

  int t = threadIdx.x, w = t >> 6, l = t & 63, l15 = l & 15, l4 = l >> 4;
  int rw = (w & 1) * 16, ch = (w >> 1) * 32;

  bf16x8 qa[2];
  {
    int m = row0 + rw + l15; if (m > 4095) m = 4095;
    const unsigned short* qp = qh + ((size_t)(h * 4096 + m)) * 64;
    qa[0] = *(const bf16x8*)(qp + l4 * 8);
    qa[1] = *(const bf16x8*)(qp + 32 + l4 * 8);
  }

  float rsum[4] = {0.f, 0.f, 0.f, 0.f};
  for (int ct = 0; ct < NKT; ct++) {
    for (int i = 0; i < 2; i++) {
      int e = t + i * 256; int r = e >> 3, c8 = e & 7;
      int kr = LO + ct * 64 + r; if (kr > 4095) kr = 4095;
      *(uint4*)&Ks[r][c8 * 8] = *(const uint4*)(kh + ((size_t)(h * 4096 + kr)) * 64 + c8 * 8);
    }
    __syncthreads();
    f32x4 acc[2] = {};
    for (int kf = 0; kf < 2; kf++)
      for (int cf = 0; cf < 2; cf++) {
        bf16x8 b = *(const bf16x8*)&Ks[ch + cf * 16 + l15][kf * 32 + l4 * 8];
        acc[cf] = __builtin_amdgcn_mfma_f32_16x16x32_bf16(qa[kf], b, acc[cf], 0, 0, 0);
      }
    for (int cf = 0; cf < 2; cf++) {
      int gc = ct * 64 + ch + cf * 16 + l15;
      bool valid = gc < LEN;
      for (int r = 0; r < 4; r++)
        rsum[r] += valid ? __expf(acc[cf][r] * 0.125f) : 0.f;
    }
    __syncthreads();
  }
  for (int r = 0; r < 4; r++) {
    float s = rsum[r];
    for (int o = 1; o < 16; o <<= 1) s += __shfl_xor(s, o, 16);
    rsum[r] = s;
  }
  if (l15 == 0)
    for (int r = 0; r < 4; r++) pd[w][l4 * 4 + r] = rsum[r];
  __syncthreads();
  if (t < 32) {
    int grow = row0 + t;
    if (grow < HI) {
      int half = t >> 4, rr = t & 15;
      Dn[h * 4096 + grow] = 1.f / (pd[half][rr] + pd[half + 2][rr]);
    }
  }
}

__global__ __launch_bounds__(256) void k_dn(const unsigned short* __restrict__ qh,
                                            const unsigned short* __restrict__ kh,
                                            float* __restrict__ Dn) {
  __shared__ unsigned short Ks[64][72];
  __shared__ float pd[4][16];
  int bid = blockIdx.x;                 // 8 heads * 129 strips
  int h = bid / 129, st = bid % 129;
  if (st < 33)      dn_body<0>(h, st * 32,               qh, kh, Dn, Ks, pd);
  else if (st < 81) dn_body<1>(h, 1025 + (st - 33) * 32, qh, kh, Dn, Ks, pd);
  else              dn_body<2>(h, 2561 + (st - 81) * 32, qh, kh, Dn, Ks, pd);
}

// ---- fused attention v4: Phase B only (Dn precomputed), fused zero-fill ----
// DLO==1: Sc[row][63] (gc=ct*64+63) belongs to quad (ct+1, qt=0, k=0). Carried in
// carry[2][32] (double-buffered: write slot ct&1, read slot (ct&1)^1).
template<int SEG>
__device__ __forceinline__ void attn_body4(int h, int row0,
    const unsigned short* __restrict__ qh, const unsigned short* __restrict__ kh,
    const unsigned short* __restrict__ vT, const float* __restrict__ Dn,
    float* __restrict__ attn, unsigned short* __restrict__ opre,
    unsigned short (&Ks)[64][72], unsigned short (&Vt)[64][72],
    unsigned short (&Sc)[32][72], float (&dn)[32], float (&carry)[2][32]) {
  constexpr int LO  = SEG == 0 ? 0 : (SEG == 1 ? 1025 : 2561);
  constexpr int HI  = SEG == 0 ? 1025 : (SEG == 1 ? 2561 : 4096);
  constexpr int LEN = HI - LO;
  constexpr int NKT = SEG == 0 ? 17 : 24;
  constexpr int CS  = SEG == 0 ? 0 : (SEG == 1 ? 1088 : 2624);
  constexpr int CQ0 = LO & ~3;          // aligned quad base of covered region
  constexpr int DLO = LO - CQ0;         // 0 or 1
  constexpr int ZQ  = SEG == 0 ? 752 : (SEG == 1 ? 639 : 640);  // zero quads/row
  constexpr int QPT = SEG == 0 ? 6 : 4; // zero quads per thread per tile-iter

  int t = threadIdx.x, w = t >> 6, l = t & 63, l15 = l & 15, l4 = l >> 4;
  int rw = (w & 1) * 16, ch = (w >> 1) * 32;

  int nvalid = HI - row0; if (nvalid > 32) nvalid = 32;
  int Z = nvalid * ZQ;
  int zc = t;
  float* abase = attn + ((size_t)h * 4096 + row0) * 4096;
  float4 z4 = make_float4(0.f, 0.f, 0.f, 0.f);

  auto zero_step = [&]() {
    for (int j = 0; j < QPT; j++) {
      int z = zc; zc += 256;
      if (z < Z) {
        int row = z / ZQ, qi = z - row * ZQ;
        int q = SEG == 0 ? qi + 272 : (SEG == 1 ? (qi < 256 ? qi : qi + 385) : qi);
        *(float4*)(abase + (size_t)row * 4096 + q * 4) = z4;
      }
    }
  };

  if (t < 32) {
    int grow = row0 + t;
    dn[t] = (grow < HI) ? Dn[h * 4096 + grow] : 0.f;
  }

  bf16x8 qa[2];
  {
    int m = row0 + rw + l15; if (m > 4095) m = 4095;
    const unsigned short* qp = qh + ((size_t)(h * 4096 + m)) * 64;
    qa[0] = *(const bf16x8*)(qp + l4 * 8);
    qa[1] = *(const bf16x8*)(qp + 32 + l4 * 8);
  }

  f32x4 pacc[2] = {};
  for (int ct = 0; ct < NKT; ct++) {
    for (int i = 0; i < 2; i++) {
      int e = t + i * 256; int r = e >> 3, c8 = e & 7;
      int kr = LO + ct * 64 + r; if (kr > 4095) kr = 4095;
      *(uint4*)&Ks[r][c8 * 8] = *(const uint4*)(kh + ((size_t)(h * 4096 + kr)) * 64 + c8 * 8);
      *(uint4*)&Vt[r][c8 * 8] = *(const uint4*)(vT + ((size_t)(h * 64 + r)) * 4160 + CS + ct * 64 + c8 * 8);
    }
    zero_step();
    __syncthreads();                    // also orders the dn[] / carry writes
    f32x4 acc[2] = {};
    for (int kf = 0; kf < 2; kf++)
      for (int cf = 0; cf < 2; cf++) {
        bf16x8 b = *(const bf16x8*)&Ks[ch + cf * 16 + l15][kf * 32 + l4 * 8];
        acc[cf] = __builtin_amdgcn_mfma_f32_16x16x32_bf16(qa[kf], b, acc[cf], 0, 0, 0);
      }
    for (int cf = 0; cf < 2; cf++)
      for (int r = 0; r < 4; r++)
        Sc[rw + l4 * 4 + r][ch + cf * 16 + l15] = f2b(__expf(acc[cf][r] * 0.125f));
    __syncthreads();
    // aligned attn quad stores: 512 quads = 32 rows x 16 quads, 2 per lane
    for (int j = 0; j < 2; j++) {
      int idx = w * 128 + j * 64 + l;
      int row = idx >> 4, qt = idx & 15;
      int grow = row0 + row;
      if (grow < HI) {
        float inv = dn[row];
        float4 o; float* po = &o.x;
        for (int k = 0; k < 4; k++) {
          int c = qt * 4 - DLO + k;
          float v = 0.f;
          if (c >= 0) {
            if (ct * 64 + c < LEN) v = b2f(Sc[row][c]) * inv;
          } else if (ct > 0) {
            v = carry[(ct & 1) ^ 1][row];   // saved at iteration ct-1
          }
          po[k] = v;
        }
        *(float4*)(abase + (size_t)row * 4096 + CQ0 + ct * 64 + qt * 4) = o;
      }
    }
    if (DLO == 1 && t < 32) {           // save Sc[row][63] into slot ct&1
      int grow = row0 + t;
      if (grow < HI) carry[ct & 1][t] = b2f(Sc[t][63]) * dn[t];
    }
    // PV
    for (int kf = 0; kf < 2; kf++) {
      bf16x8 ap = *(const bf16x8*)&Sc[rw + l15][kf * 32 + l4 * 8];
      for (int cf = 0; cf < 2; cf++) {
        bf16x8 b = *(const bf16x8*)&Vt[ch + cf * 16 + l15][kf * 32 + l4 * 8];
        pacc[cf] = __builtin_amdgcn_mfma_f32_16x16x32_bf16(ap, b, pacc[cf], 0, 0, 0);
      }
    }
    __syncthreads();
  }
  if (SEG == 1 && t < 32) {             // final col 2560 (gc=1535) from last carry (ct=23 -> slot 1)
    int grow = row0 + t;
    if (grow < HI)
      *(float4*)(abase + (size_t)t * 4096 + 2560) = make_float4(carry[(NKT - 1) & 1][t], 0.f, 0.f, 0.f);
  }

  for (int cf = 0; cf < 2; cf++)
    for (int r = 0; r < 4; r++) {
      int lrow = rw + l4 * 4 + r;
      int grow = row0 + lrow;
      if (grow < HI)
        opre[(size_t)grow * 512 + h * 64 + ch + cf * 16 + l15] = f2b(pacc[cf][r] * dn[lrow]);
    }
}

__global__ __launch_bounds__(256) void k_attn4(const unsigned short* __restrict__ qh,
                                               const unsigned short* __restrict__ kh,
                                               const unsigned short* __restrict__ vT,
                                               const float* __restrict__ Dn,
                                               float* __restrict__ attn,
                                               unsigned short* __restrict__ opre) {
  __shared__ unsigned short Ks[64][72];
  __shared__ unsigned short Vt[64][72];
  __shared__ unsigned short Sc[32][72];
  __shared__ float dn[32];
  __shared__ float carry[2][32];
  int bid = blockIdx.x;                 // 8 heads * 129 strips
  int h = bid / 129, st = bid % 129;
  if (st < 33)      attn_body4<0>(h, st * 32,               qh, kh, vT, Dn, attn, opre, Ks, Vt, Sc, dn, carry);
  else if (st < 81) attn_body4<1>(h, 1025 + (st - 33) * 32, qh, kh, vT, Dn, attn, opre, Ks, Vt, Sc, dn, carry);
  else              attn_body4<2>(h, 2561 + (st - 81) * 32, qh, kh, vT, Dn, attn, opre, Ks, Vt, Sc, dn, carry);
}

extern "C" void kernel_launch(void* const* d_in, const int* in_sizes, int n_in,
                              void* d_out, int out_size, void* d_ws, size_t ws_size,
                              hipStream_t stream) {
  const float* hidden = (const float*)d_in[0];
  const float* qkv_w  = (const float*)d_in[1];
  const float* qkv_b  = (const float*)d_in[2];
  const float* proj_w = (const float*)d_in[3];
  const float* proj_b = (const float*)d_in[4];

  char* p = (char*)d_ws;
  auto alloc = [&](size_t bytes) { char* r = p; p += (bytes + 255) & ~(size_t)255; return r; };
  float*          cosT   = (float*)alloc((size_t)4096 * 32 * 4);
  float*          sinT   = (float*)alloc((size_t)4096 * 32 * 4);
  unsigned short* xb     = (unsigned short*)alloc((size_t)4096 * 512 * 2);
  unsigned short* wqkvT  = (unsigned short*)alloc((size_t)1536 * 512 * 2);
  unsigned short* wprojT = (unsigned short*)alloc((size_t)512 * 512 * 2);
  unsigned short* qhb    = (unsigned short*)alloc((size_t)8 * 4096 * 64 * 2);
  unsigned short* khb    = (unsigned short*)alloc((size_t)8 * 4096 * 64 * 2);
  unsigned short* vTb    = (unsigned short*)alloc((size_t)8 * 64 * 4160 * 2);
  unsigned short* opre   = (unsigned short*)alloc((size_t)4096 * 512 * 2);
  float*          Dnb    = (float*)alloc((size_t)8 * 4096 * 4);

  float* final_out = (float*)d_out;                       // [4096][512]
  float* attn_out  = (float*)d_out + (size_t)4096 * 512;  // [8][4096][4096]

  k_tables<<<dim3(512), dim3(256), 0, stream>>>(cosT, sinT);
  k_vpad<<<dim3(8), dim3(256), 0, stream>>>(vTb);
  k_cvt<<<dim3(2048), dim3(256), 0, stream>>>(hidden, xb, 4096 * 512 / 4);
  k_twcvt<<<dim3(16, 48), dim3(256), 0, stream>>>(qkv_w, wqkvT, 512, 1536);
  k_twcvt<<<dim3(16, 16), dim3(256), 0, stream>>>(proj_w, wprojT, 512, 512);
  k_gemm_qkv<<<dim3(64, 24), dim3(256), 0, stream>>>(xb, wqkvT, qkv_b, cosT, sinT, qhb, khb, vTb);
  k_dn<<<dim3(8 * 129), dim3(256), 0, stream>>>(qhb, khb, Dnb);
  k_attn4<<<dim3(8 * 129), dim3(256), 0, stream>>>(qhb, khb, vTb, Dnb, attn_out, opre);
  k_gemm<<<dim3(64, 8), dim3(256), 0, stream>>>(opre, wprojT, proj_b, final_out, 4096, 512, 512);
}

// Round 9
// 181.194 us; speedup vs baseline: 1.0990x; 1.0990x over previous
//
#include <hip/hip_runtime.h>
#include <math.h>

typedef short bf16x8 __attribute__((ext_vector_type(8)));
typedef float f32x4 __attribute__((ext_vector_type(4)));
typedef unsigned short u16x8 __attribute__((ext_vector_type(8)));

// Segments (cu_seqlens=[0,1024,2560,4096], searchsorted side='left'):
// seg0 [0,1025) len1025 ; seg1 [1025,2561) len1536 ; seg2 [2561,4096) len1535
// vT packed cols: pc(s) = s<1025 ? s : s+63 (seg0 @0 pad->1088, seg1 @1088, seg2 @2624); width 4160

__device__ __forceinline__ unsigned short f2b(float f) {
  union { float f; unsigned int u; } v; v.f = f;
  unsigned int u = v.u;
  return (unsigned short)((u + 0x7FFFu + ((u >> 16) & 1u)) >> 16);  // RTNE
}
__device__ __forceinline__ float b2f(unsigned short h) {
  union { unsigned int u; float f; } v; v.u = ((unsigned int)h) << 16; return v.f;
}

// ---- RoPE cos/sin table: [4096][32] each, f32 ----
__global__ __launch_bounds__(256) void k_tables(float* __restrict__ cosT, float* __restrict__ sinT) {
  int idx = blockIdx.x * 256 + threadIdx.x;
  if (idx >= 4096 * 32) return;
  int pos = idx >> 5, i = idx & 31;
  float invf = (float)(1.0 / pow(10000.0, (double)i / 32.0));
  float ang = (float)pos * invf;
  cosT[idx] = cosf(ang);
  sinT[idx] = sinf(ang);
}

// ---- zero vT pad columns (runs BEFORE k_gemm_qkv) ----
__global__ __launch_bounds__(256) void k_vpad(unsigned short* __restrict__ vT) {
  int h = blockIdx.x, t = threadIdx.x;
  for (int i = t; i < 64 * 64; i += 256) {
    int d = i >> 6, c = i & 63;
    vT[((size_t)(h * 64 + d)) * 4160 + 1024 + c] = 0;
  }
  if (t < 64) vT[((size_t)(h * 64 + t)) * 4160 + 4159] = 0;
}

__global__ __launch_bounds__(256) void k_cvt(const float* __restrict__ x, unsigned short* __restrict__ xb, int n4) {
  int idx = blockIdx.x * 256 + threadIdx.x;
  if (idx >= n4) return;
  float4 v = ((const float4*)x)[idx];
  ushort4 o; o.x = f2b(v.x); o.y = f2b(v.y); o.z = f2b(v.z); o.w = f2b(v.w);
  ((ushort4*)xb)[idx] = o;
}

__global__ __launch_bounds__(256) void k_twcvt(const float* __restrict__ src, unsigned short* __restrict__ dst,
                                               int K, int N) {
  __shared__ float tile[32][33];
  int k0 = blockIdx.x * 32, n0 = blockIdx.y * 32;
  int t = threadIdx.x;
  for (int i = 0; i < 4; i++) {
    int e = t + i * 256; int r = e >> 5, c = e & 31;
    tile[r][c] = src[(size_t)(k0 + r) * N + n0 + c];
  }
  __syncthreads();
  for (int i = 0; i < 4; i++) {
    int e = t + i * 256; int r = e >> 5, c = e & 31;
    dst[(size_t)(n0 + r) * K + k0 + c] = f2b(tile[c][r]);
  }
}

// ---- generic NT GEMM (used for proj): C = A * Bt^T + bias, f32 out ----
__global__ __launch_bounds__(256) void k_gemm(const unsigned short* __restrict__ A,
                                              const unsigned short* __restrict__ Bt,
                                              const float* __restrict__ bias,
                                              float* __restrict__ C,
                                              int M, int N, int K) {
  __shared__ unsigned short As[64][72];
  __shared__ unsigned short Bs[64][72];
  int row0 = blockIdx.x * 64, col0 = blockIdx.y * 64;
  int t = threadIdx.x, w = t >> 6, l = t & 63;
  int l15 = l & 15, l4 = l >> 4;
  f32x4 acc[4] = {};
  for (int k0 = 0; k0 < K; k0 += 64) {
    for (int i = 0; i < 2; i++) {
      int e = t + i * 256; int r = e >> 3, c8 = e & 7;
      *(uint4*)&As[r][c8 * 8] = *(const uint4*)(A + (size_t)(row0 + r) * K + k0 + c8 * 8);
      *(uint4*)&Bs[r][c8 * 8] = *(const uint4*)(Bt + (size_t)(col0 + r) * K + k0 + c8 * 8);
    }
    __syncthreads();
    for (int kh = 0; kh < 2; kh++) {
      bf16x8 a = *(const bf16x8*)&As[w * 16 + l15][kh * 32 + l4 * 8];
      for (int cf = 0; cf < 4; cf++) {
        bf16x8 b = *(const bf16x8*)&Bs[cf * 16 + l15][kh * 32 + l4 * 8];
        acc[cf] = __builtin_amdgcn_mfma_f32_16x16x32_bf16(a, b, acc[cf], 0, 0, 0);
      }
    }
    __syncthreads();
  }
  for (int cf = 0; cf < 4; cf++) {
    int col = col0 + cf * 16 + l15;
    float bv = bias[col];
    for (int r = 0; r < 4; r++) {
      int row = row0 + w * 16 + l4 * 4 + r;
      C[(size_t)row * N + col] = acc[cf][r] + bv;
    }
  }
}

// ---- qkv GEMM with fused bias + RoPE + head-split + V-transpose epilogue ----
__global__ __launch_bounds__(256) void k_gemm_qkv(const unsigned short* __restrict__ A,
                                                  const unsigned short* __restrict__ Bt,
                                                  const float* __restrict__ bias,
                                                  const float* __restrict__ cosT,
                                                  const float* __restrict__ sinT,
                                                  unsigned short* __restrict__ qh,
                                                  unsigned short* __restrict__ kh,
                                                  unsigned short* __restrict__ vT) {
  __shared__ unsigned short As[64][72];
  __shared__ unsigned short Bs[64][72];
  int row0 = blockIdx.x * 64, col0 = blockIdx.y * 64;
  int t = threadIdx.x, w = t >> 6, l = t & 63;
  int l15 = l & 15, l4 = l >> 4;
  f32x4 acc[4] = {};
  for (int k0 = 0; k0 < 512; k0 += 64) {
    for (int i = 0; i < 2; i++) {
      int e = t + i * 256; int r = e >> 3, c8 = e & 7;
      *(uint4*)&As[r][c8 * 8] = *(const uint4*)(A + (size_t)(row0 + r) * 512 + k0 + c8 * 8);
      *(uint4*)&Bs[r][c8 * 8] = *(const uint4*)(Bt + (size_t)(col0 + r) * 512 + k0 + c8 * 8);
    }
    __syncthreads();
    for (int kk = 0; kk < 2; kk++) {
      bf16x8 a = *(const bf16x8*)&As[w * 16 + l15][kk * 32 + l4 * 8];
      for (int cf = 0; cf < 4; cf++) {
        bf16x8 b = *(const bf16x8*)&Bs[cf * 16 + l15][kk * 32 + l4 * 8];
        acc[cf] = __builtin_amdgcn_mfma_f32_16x16x32_bf16(a, b, acc[cf], 0, 0, 0);
      }
    }
    __syncthreads();
  }
  for (int cf = 0; cf < 4; cf++) {
    float bv = bias[col0 + cf * 16 + l15];
    for (int r = 0; r < 4; r++) acc[cf][r] += bv;
  }
  int kind = col0 >> 9;                 // 0=q, 1=k, 2=v
  int h = (col0 & 511) >> 6;
  if (kind < 2) {
    for (int r = 0; r < 4; r++) {
      int row = row0 + w * 16 + l4 * 4 + r;
      float c0 = cosT[row * 32 + l15],      s0 = sinT[row * 32 + l15];
      float c1 = cosT[row * 32 + 16 + l15], s1 = sinT[row * 32 + 16 + l15];
      float q0 = acc[0][r], q1 = acc[1][r], q2 = acc[2][r], q3 = acc[3][r];
      int rl = w * 16 + l4 * 4 + r;
      As[rl][0 * 16 + l15] = f2b(q0 * c0 - q2 * s0);
      As[rl][1 * 16 + l15] = f2b(q1 * c1 - q3 * s1);
      As[rl][2 * 16 + l15] = f2b(q2 * c0 + q0 * s0);
      As[rl][3 * 16 + l15] = f2b(q3 * c1 + q1 * s1);
    }
  } else {
    for (int cf = 0; cf < 4; cf++)
      for (int r = 0; r < 4; r++)
        As[w * 16 + l4 * 4 + r][cf * 16 + l15] = f2b(acc[cf][r]);
  }
  __syncthreads();
  if (kind < 2) {
    unsigned short* dst = (kind == 0 ? qh : kh);
    for (int p = 0; p < 2; p++) {
      int idx = p * 256 + t;
      int rl = idx >> 3, c8 = (idx & 7) * 8;
      *(u16x8*)(dst + ((size_t)(h * 4096 + row0 + rl)) * 64 + c8) = *(const u16x8*)&As[rl][c8];
    }
  } else {
    for (int p = 0; p < 2; p++) {
      int idx = p * 256 + t;
      int d = idx >> 3, s8 = (idx & 7) * 8;
      int sbase = row0 + s8;
      u16x8 val;
      for (int j = 0; j < 8; j++) val[j] = As[s8 + j][d];
      unsigned short* vrow = vT + ((size_t)(h * 64 + d)) * 4160;
      if (sbase != 1024) {
        int pc = (sbase < 1025) ? sbase : sbase + 63;
        *(u16x8*)(vrow + pc) = val;
      } else {
        for (int j = 0; j < 8; j++) {
          int s = sbase + j;
          vrow[(s < 1025) ? s : s + 63] = val[j];
        }
      }
    }
  }
}

// ---- fused attention v3: 32-row strips, fused zero-fill, templated per segment ----
// DLO==1: Sc[row][63] (gc=ct*64+63) belongs to quad (ct+1, qt=0, k=0). Carried in
// carry[2][32]: write slot ct&1, read slot (ct&1)^1 — double-buffered to avoid the
// cross-wave race (readers of rows 8..31 are waves 1-3; writer is wave 0).
template<int SEG>
__device__ __forceinline__ void attn_body(int h, int row0,
    const unsigned short* __restrict__ qh, const unsigned short* __restrict__ kh,
    const unsigned short* __restrict__ vT, float* __restrict__ attn,
    unsigned short* __restrict__ opre,
    unsigned short (&Ks)[64][72], unsigned short (&Vt)[64][72],
    unsigned short (&Sc)[32][72], float (&pd)[4][16], float (&dn)[32],
    float (&carry)[2][32]) {
  constexpr int LO  = SEG == 0 ? 0 : (SEG == 1 ? 1025 : 2561);
  constexpr int HI  = SEG == 0 ? 1025 : (SEG == 1 ? 2561 : 4096);
  constexpr int LEN = HI - LO;
  constexpr int NKT = SEG == 0 ? 17 : 24;
  constexpr int CS  = SEG == 0 ? 0 : (SEG == 1 ? 1088 : 2624);
  constexpr int CQ0 = LO & ~3;          // aligned quad base of covered region
  constexpr int DLO = LO - CQ0;         // 0 or 1
  constexpr int ZQ  = SEG == 0 ? 752 : (SEG == 1 ? 639 : 640);  // zero quads/row
  constexpr int QPT = SEG == 0 ? 3 : 2; // zero quads per thread per tile-iter

  int t = threadIdx.x, w = t >> 6, l = t & 63, l15 = l & 15, l4 = l >> 4;
  int rw = (w & 1) * 16, ch = (w >> 1) * 32;

  int nvalid = HI - row0; if (nvalid > 32) nvalid = 32;
  int Z = nvalid * ZQ;
  int zc = t;
  float* abase = attn + ((size_t)h * 4096 + row0) * 4096;
  float4 z4 = make_float4(0.f, 0.f, 0.f, 0.f);

  auto zero_step = [&]() {
    for (int j = 0; j < QPT; j++) {
      int z = zc; zc += 256;
      if (z < Z) {
        int row = z / ZQ, qi = z - row * ZQ;
        int q = SEG == 0 ? qi + 272 : (SEG == 1 ? (qi < 256 ? qi : qi + 385) : qi);
        *(float4*)(abase + (size_t)row * 4096 + q * 4) = z4;
      }
    }
  };

  bf16x8 qa[2];
  {
    int m = row0 + rw + l15; if (m > 4095) m = 4095;
    const unsigned short* qp = qh + ((size_t)(h * 4096 + m)) * 64;
    qa[0] = *(const bf16x8*)(qp + l4 * 8);
    qa[1] = *(const bf16x8*)(qp + 32 + l4 * 8);
  }

  // ---- Phase A: row sums of exp(s*0.125) ----
  float rsum[4] = {0.f, 0.f, 0.f, 0.f};
  for (int ct = 0; ct < NKT; ct++) {
    for (int i = 0; i < 2; i++) {
      int e = t + i * 256; int r = e >> 3, c8 = e & 7;
      int kr = LO + ct * 64 + r; if (kr > 4095) kr = 4095;
      *(uint4*)&Ks[r][c8 * 8] = *(const uint4*)(kh + ((size_t)(h * 4096 + kr)) * 64 + c8 * 8);
    }
    zero_step();
    __syncthreads();
    f32x4 acc[2] = {};
    for (int kf = 0; kf < 2; kf++)
      for (int cf = 0; cf < 2; cf++) {
        bf16x8 b = *(const bf16x8*)&Ks[ch + cf * 16 + l15][kf * 32 + l4 * 8];
        acc[cf] = __builtin_amdgcn_mfma_f32_16x16x32_bf16(qa[kf], b, acc[cf], 0, 0, 0);
      }
    for (int cf = 0; cf < 2; cf++) {
      int gc = ct * 64 + ch + cf * 16 + l15;
      bool valid = gc < LEN;
      for (int r = 0; r < 4; r++)
        rsum[r] += valid ? __expf(acc[cf][r] * 0.125f) : 0.f;
    }
    __syncthreads();
  }
  for (int r = 0; r < 4; r++) {
    float s = rsum[r];
    for (int o = 1; o < 16; o <<= 1) s += __shfl_xor(s, o, 16);
    rsum[r] = s;
  }
  if (l15 == 0)
    for (int r = 0; r < 4; r++) pd[w][l4 * 4 + r] = rsum[r];
  __syncthreads();
  if (t < 32) {
    int half = t >> 4, rr = t & 15;
    dn[t] = 1.f / (pd[half][rr] + pd[half + 2][rr]);
  }
  __syncthreads();

  // ---- Phase B: recompute scores; attn quads (incl. leading/trailing zeros); PV ----
  f32x4 pacc[2] = {};
  for (int ct = 0; ct < NKT; ct++) {
    for (int i = 0; i < 2; i++) {
      int e = t + i * 256; int r = e >> 3, c8 = e & 7;
      int kr = LO + ct * 64 + r; if (kr > 4095) kr = 4095;
      *(uint4*)&Ks[r][c8 * 8] = *(const uint4*)(kh + ((size_t)(h * 4096 + kr)) * 64 + c8 * 8);
      *(uint4*)&Vt[r][c8 * 8] = *(const uint4*)(vT + ((size_t)(h * 64 + r)) * 4160 + CS + ct * 64 + c8 * 8);
    }
    zero_step();
    __syncthreads();
    f32x4 acc[2] = {};
    for (int kf = 0; kf < 2; kf++)
      for (int cf = 0; cf < 2; cf++) {
        bf16x8 b = *(const bf16x8*)&Ks[ch + cf * 16 + l15][kf * 32 + l4 * 8];
        acc[cf] = __builtin_amdgcn_mfma_f32_16x16x32_bf16(qa[kf], b, acc[cf], 0, 0, 0);
      }
    for (int cf = 0; cf < 2; cf++)
      for (int r = 0; r < 4; r++)
        Sc[rw + l4 * 4 + r][ch + cf * 16 + l15] = f2b(__expf(acc[cf][r] * 0.125f));
    __syncthreads();
    // aligned attn quad stores: 512 quads = 32 rows x 16 quads, 2 per lane
    for (int j = 0; j < 2; j++) {
      int idx = w * 128 + j * 64 + l;
      int row = idx >> 4, qt = idx & 15;
      int grow = row0 + row;
      if (grow < HI) {
        float inv = dn[row];
        float4 o; float* po = &o.x;
        for (int k = 0; k < 4; k++) {
          int c = qt * 4 - DLO + k;
          float v = 0.f;
          if (c >= 0) {
            if (ct * 64 + c < LEN) v = b2f(Sc[row][c]) * inv;
          } else if (ct > 0) {
            v = carry[(ct & 1) ^ 1][row];   // saved at iteration ct-1
          }
          po[k] = v;
        }
        *(float4*)(abase + (size_t)row * 4096 + CQ0 + ct * 64 + qt * 4) = o;
      }
    }
    if (DLO == 1 && t < 32) {           // save Sc[row][63] into slot ct&1
      int grow = row0 + t;
      if (grow < HI) carry[ct & 1][t] = b2f(Sc[t][63]) * dn[t];
    }
    // PV
    for (int kf = 0; kf < 2; kf++) {
      bf16x8 ap = *(const bf16x8*)&Sc[rw + l15][kf * 32 + l4 * 8];
      for (int cf = 0; cf < 2; cf++) {
        bf16x8 b = *(const bf16x8*)&Vt[ch + cf * 16 + l15][kf * 32 + l4 * 8];
        pacc[cf] = __builtin_amdgcn_mfma_f32_16x16x32_bf16(ap, b, pacc[cf], 0, 0, 0);
      }
    }
    __syncthreads();
  }
  if (SEG == 1 && t < 32) {             // final col 2560 (gc=1535) from last carry (ct=23 -> slot 1)
    int grow = row0 + t;
    if (grow < HI)
      *(float4*)(abase + (size_t)t * 4096 + 2560) = make_float4(carry[(NKT - 1) & 1][t], 0.f, 0.f, 0.f);
  }

  for (int cf = 0; cf < 2; cf++)
    for (int r = 0; r < 4; r++) {
      int lrow = rw + l4 * 4 + r;
      int grow = row0 + lrow;
      if (grow < HI)
        opre[(size_t)grow * 512 + h * 64 + ch + cf * 16 + l15] = f2b(pacc[cf][r] * dn[lrow]);
    }
}

// __launch_bounds__(256, 4): cap VGPRs at 128 -> 4 waves/SIMD -> 4 blocks/CU
// (was 132 VGPR = 3 blocks/CU; kernel is store-rate limited, +33% TLP)
__global__ __launch_bounds__(256, 4) void k_attn3(const unsigned short* __restrict__ qh,
                                               const unsigned short* __restrict__ kh,
                                               const unsigned short* __restrict__ vT,
                                               float* __restrict__ attn,
                                               unsigned short* __restrict__ opre) {
  __shared__ unsigned short Ks[64][72];
  __shared__ unsigned short Vt[64][72];
  __shared__ unsigned short Sc[32][72];
  __shared__ float pd[4][16];
  __shared__ float dn[32];
  __shared__ float carry[2][32];
  int bid = blockIdx.x;                 // 8 heads * 129 strips
  int h = bid / 129, st = bid % 129;
  if (st < 33)      attn_body<0>(h, st * 32,               qh, kh, vT, attn, opre, Ks, Vt, Sc, pd, dn, carry);
  else if (st < 81) attn_body<1>(h, 1025 + (st - 33) * 32, qh, kh, vT, attn, opre, Ks, Vt, Sc, pd, dn, carry);
  else              attn_body<2>(h, 2561 + (st - 81) * 32, qh, kh, vT, attn, opre, Ks, Vt, Sc, pd, dn, carry);
}

extern "C" void kernel_launch(void* const* d_in, const int* in_sizes, int n_in,
                              void* d_out, int out_size, void* d_ws, size_t ws_size,
                              hipStream_t stream) {
  const float* hidden = (const float*)d_in[0];
  const float* qkv_w  = (const float*)d_in[1];
  const float* qkv_b  = (const float*)d_in[2];
  const float* proj_w = (const float*)d_in[3];
  const float* proj_b = (const float*)d_in[4];

  char* p = (char*)d_ws;
  auto alloc = [&](size_t bytes) { char* r = p; p += (bytes + 255) & ~(size_t)255; return r; };
  float*          cosT   = (float*)alloc((size_t)4096 * 32 * 4);
  float*          sinT   = (float*)alloc((size_t)4096 * 32 * 4);
  unsigned short* xb     = (unsigned short*)alloc((size_t)4096 * 512 * 2);
  unsigned short* wqkvT  = (unsigned short*)alloc((size_t)1536 * 512 * 2);
  unsigned short* wprojT = (unsigned short*)alloc((size_t)512 * 512 * 2);
  unsigned short* qhb    = (unsigned short*)alloc((size_t)8 * 4096 * 64 * 2);
  unsigned short* khb    = (unsigned short*)alloc((size_t)8 * 4096 * 64 * 2);
  unsigned short* vTb    = (unsigned short*)alloc((size_t)8 * 64 * 4160 * 2);
  unsigned short* opre   = (unsigned short*)alloc((size_t)4096 * 512 * 2);

  float* final_out = (float*)d_out;                       // [4096][512]
  float* attn_out  = (float*)d_out + (size_t)4096 * 512;  // [8][4096][4096]

  k_tables<<<dim3(512), dim3(256), 0, stream>>>(cosT, sinT);
  k_vpad<<<dim3(8), dim3(256), 0, stream>>>(vTb);
  k_cvt<<<dim3(2048), dim3(256), 0, stream>>>(hidden, xb, 4096 * 512 / 4);
  k_twcvt<<<dim3(16, 48), dim3(256), 0, stream>>>(qkv_w, wqkvT, 512, 1536);
  k_twcvt<<<dim3(16, 16), dim3(256), 0, stream>>>(proj_w, wprojT, 512, 512);
  k_gemm_qkv<<<dim3(64, 24), dim3(256), 0, stream>>>(xb, wqkvT, qkv_b, cosT, sinT, qhb, khb, vTb);
  k_attn3<<<dim3(8 * 129), dim3(256), 0, stream>>>(qhb, khb, vTb, attn_out, opre);
  k_gemm<<<dim3(64, 8), dim3(256), 0, stream>>>(opre, wprojT, proj_b, final_out, 4096, 512, 512);
}